// Round 1
// 191.340 us; speedup vs baseline: 1.0630x; 1.0630x over previous
//
#include <hip/hip_runtime.h>
#include <hip/hip_bf16.h>

// RecognitionLattice: RNN-T style lattice loss.
// k_front: fproj GEMM (direct fp32-Wf transpose staging, f16 out) + Wo->fp8
//          shuffle + cemb gather (f16) as block ranges of ONE launch
// -> k_joint: h=tanh(fproj+cemb) packed-f16 -> fp8 @ Wo_fp8, BK=64 K-loop.
//    RETILED: 8 waves = 8 M-slots, each wave 16 rows x 288 cols. A-fragments
//    are computed IN REGISTERS (lane's tanh output == its MFMA A-frag:
//    row=lane&15, k-octet=lane>>4) -- no A LDS round trip, no lgkm barrier
//    dependency, B-only double-buffered LDS via global_load_lds. Epilogue LSE
//    is fully in-wave (wave owns whole rows): no cross-wave combine LDS.
// -> k_compact: parallel depth-4 semiring compaction -> Dg
// -> k_dpser: 1 wave/batch serial chain, 128 banded-lse5 steps, 8-deep reg ring.

#define BB 4
#define TT 512
#define UU 96
#define FF 512
#define HH 512
#define VV 256
#define NV (VV + 1)    // 257 vocab incl. blank
#define NU (UU + 1)    // 97 lattice rows per t
#define NP 288         // 18*16 padded N
#define NEG_INF (-1e30f)
#define LOG2E 1.4426950408889634f
#define LN2 0.6931471805599453f
#define NG 128         // groups of 4 t-steps
#define GSTRIDE 520    // 5*104 floats per group operator
#define WOSCL 64.0f    // Wo pre-scale into fp8 normal range
#define INVWOSCL 0.015625f

typedef _Float16 f16;
typedef __attribute__((ext_vector_type(8))) _Float16 f16x8;
typedef __bf16 bf16;
typedef __bf16 bf16x8 __attribute__((ext_vector_type(8)));
typedef float f32x4 __attribute__((ext_vector_type(4)));

__device__ __forceinline__ f16x8 splat8(float s) {
    f16 v = (f16)s;
    f16x8 r = {v, v, v, v, v, v, v, v};
    return r;
}

// tanh via clamped odd polynomial in PACKED f16 (v_pk_* dual-issue), then
// fp8 e4m3 pack. Max poly err ~0.007 on [-2,2]; f16 intermediate err ~1e-3
// << fp8 output quantization.
__device__ __forceinline__ long tanh_pack8(f16x8 fv8, f16x8 cv8) {
    f16x8 x = fv8 + cv8;
    x = __builtin_elementwise_min(__builtin_elementwise_max(x, splat8(-2.0f)),
                                  splat8(2.0f));
    f16x8 y = x * x;
    f16x8 q = y * splat8(-0.0067528f) + splat8(0.0700672f);
    q = y * q + splat8(-0.301720f);
    q = y * q + splat8(1.0f);
    f16x8 t = x * q;
    int lo = 0, hi = 0;
    lo = __builtin_amdgcn_cvt_pk_fp8_f32((float)t[0], (float)t[1], lo, false);
    lo = __builtin_amdgcn_cvt_pk_fp8_f32((float)t[2], (float)t[3], lo, true);
    hi = __builtin_amdgcn_cvt_pk_fp8_f32((float)t[4], (float)t[5], hi, false);
    hi = __builtin_amdgcn_cvt_pk_fp8_f32((float)t[6], (float)t[7], hi, true);
    return (long)(((unsigned long long)(unsigned int)lo) |
                  (((unsigned long long)(unsigned int)hi) << 32));
}

// pack 8 floats -> 8 fp8 e4m3 (for Wo prep)
__device__ __forceinline__ long pack_fp8x8(const float* v) {
    int lo = 0, hi = 0;
    lo = __builtin_amdgcn_cvt_pk_fp8_f32(v[0], v[1], lo, false);
    lo = __builtin_amdgcn_cvt_pk_fp8_f32(v[2], v[3], lo, true);
    hi = __builtin_amdgcn_cvt_pk_fp8_f32(v[4], v[5], hi, false);
    hi = __builtin_amdgcn_cvt_pk_fp8_f32(v[6], v[7], hi, true);
    return (long)(((unsigned long long)(unsigned int)lo) |
                  (((unsigned long long)(unsigned int)hi) << 32));
}

// base-2 log-domain ops (inputs/outputs already scaled by log2(e))
__device__ __forceinline__ float lae2(float x, float y) {
    float m = fmaxf(x, y);
    float d = fminf(x, y) - m;
    return m + __builtin_amdgcn_logf(1.0f + __builtin_amdgcn_exp2f(d));
}

__device__ __forceinline__ float lse3_2(float x, float y, float z) {
    float m = fmaxf(fmaxf(x, y), z);
    float s = __builtin_amdgcn_exp2f(x - m) + __builtin_amdgcn_exp2f(y - m) +
              __builtin_amdgcn_exp2f(z - m);
    return m + __builtin_amdgcn_logf(s);
}

__device__ __forceinline__ float lse5_2(float a, float b, float c, float d, float e) {
    float m = fmaxf(fmaxf(fmaxf(a, b), fmaxf(c, d)), e);
    float s = __builtin_amdgcn_exp2f(a - m) + __builtin_amdgcn_exp2f(b - m) +
              __builtin_amdgcn_exp2f(c - m) + __builtin_amdgcn_exp2f(d - m) +
              __builtin_amdgcn_exp2f(e - m);
    return m + __builtin_amdgcn_logf(s);
}

__device__ __forceinline__ void async_copy16(const void* g, void* l) {
    __builtin_amdgcn_global_load_lds(
        (const __attribute__((address_space(1))) unsigned int*)g,
        (__attribute__((address_space(3))) unsigned int*)l, 16, 0, 0);
}

// ---- front: fproj GEMM + Wo->fp8 shuffle + cemb gather
__global__ __launch_bounds__(256, 2) void k_front(
    const float* __restrict__ frames, const float* __restrict__ Wf,
    const float* __restrict__ Wo, const float* __restrict__ E,
    const int* __restrict__ labels, f16* __restrict__ fproj,
    long* __restrict__ Wo_s, f16* __restrict__ cemb) {
    __shared__ bf16 Alds[64 * 40];
    __shared__ bf16 Blds[64 * 40];
    const int blk = blockIdx.x;
    const int tid = threadIdx.x;

    if (blk < 256) {
        const int r0 = (blk & 31) * 64;
        const int n0 = (blk >> 5) * 64;
        const int lane = tid & 63, w = tid >> 6;
        const int c = lane & 15, g = lane >> 4;

        const int srow = tid >> 2, sko = (tid & 3) * 8;
        const float* fptr = frames + (size_t)(r0 + srow) * FF + sko;
        const int q = tid >> 6, c64 = tid & 63;  // B-transpose staging coords

        f32x4 acc[4];
#pragma unroll
        for (int j = 0; j < 4; ++j) acc[j] = (f32x4){0.f, 0.f, 0.f, 0.f};

        for (int kt = 0; kt < FF; kt += 32) {
            float4 f1 = *(const float4*)(fptr + kt);
            float4 f2 = *(const float4*)(fptr + kt + 4);
            bf16x8 av = {(bf16)f1.x, (bf16)f1.y, (bf16)f1.z, (bf16)f1.w,
                         (bf16)f2.x, (bf16)f2.y, (bf16)f2.z, (bf16)f2.w};
            *(bf16x8*)&Alds[srow * 40 + sko] = av;
#pragma unroll
            for (int p = 0; p < 8; ++p) {
                float v = Wf[(size_t)(kt + q * 8 + p) * HH + n0 + c64];
                Blds[c64 * 40 + q * 8 + p] = (bf16)v;
            }
            __syncthreads();
            const int m = w * 16;
            bf16x8 af = *(const bf16x8*)&Alds[(m + c) * 40 + g * 8];
#pragma unroll
            for (int j = 0; j < 4; ++j) {
                bf16x8 bv = *(const bf16x8*)&Blds[(j * 16 + c) * 40 + g * 8];
                acc[j] = __builtin_amdgcn_mfma_f32_16x16x32_bf16(af, bv, acc[j], 0, 0, 0);
            }
            __syncthreads();
        }
        const int m = w * 16;
#pragma unroll
        for (int j = 0; j < 4; ++j)
#pragma unroll
            for (int r = 0; r < 4; ++r)
                fproj[(size_t)(r0 + m + g * 4 + r) * HH + n0 + j * 16 + c] = (f16)acc[j][r];
    } else if (blk < 328) {
        int idx = (blk - 256) * 256 + tid;  // 0..18431
        int n = idx % NP;
        int rest = idx / NP;
        int kg = rest & 3;
        int k32 = rest >> 2;
        float v[8];
#pragma unroll
        for (int e = 0; e < 8; ++e) {
            int k = k32 * 32 + kg * 8 + e;
            v[e] = (n < NV) ? Wo[k * NV + n] * WOSCL : 0.f;
        }
        Wo_s[idx] = pack_fp8x8(v);
    } else {
        int u = blk - 328;  // 0..96
        for (int b = 0; b < BB; ++b) {
            int ctx = (u == 0) ? 0 : labels[b * UU + (u - 1)];
            const float* src = E + (size_t)ctx * HH;
            f16* dst = cemb + ((size_t)b * NU + u) * HH;
            for (int i = tid; i < HH; i += 256) dst[i] = (f16)src[i];
        }
    }
}

// ---- joint: logits = tanh(fproj[t]+cemb[u]) @ Wo  [fp8 MFMA, BK=64 K-loop]
// grid (388, B), block 512 = 8 waves = 8 M-slots of 16 rows; each wave owns
// 16 rows x 288 cols (acc[18] f32x4 = 72 VGPR). A-fragments computed in
// registers: lane (c=lane&15, g=lane>>4) tanh-packs row (w*16+c), k-octet g
// directly into the MFMA A operand. Only B is LDS-staged (double-buffered
// global_load_lds, issued at iter top -> full MFMA phase of flight). One
// barrier per 64-k chunk, no lgkm A dependency. Fully in-wave LSE epilogue.
__global__ __launch_bounds__(512, 4) void k_joint(
    const f16* __restrict__ fproj, const f16* __restrict__ cemb,
    const long* __restrict__ Wo_s, const int* __restrict__ labels,
    const int* __restrict__ num_frames, float* __restrict__ cl_arr) {
    __shared__ long B_s8[2][2304];  // 2 x 18432 B; [s(k32)][kg][n] longs

    const int tid = threadIdx.x;
    const int b = blockIdx.y;
    const int r0 = blockIdx.x * 128;
    const int nf = num_frames[b];
    if (r0 / NU >= nf) return;  // whole tile beyond active frames: outputs unused

    const int lane = tid & 63, w = tid >> 6;
    const int c = lane & 15, g = lane >> 4;

    // This lane's A row and k-octet: row = w*16 + c, k = g*8 + s*32 + i*64.
    const int gr = r0 + w * 16 + c;
    const int at = gr / NU, au = gr - at * NU;
    const f16* pf = fproj + ((size_t)(b * TT + at)) * HH + g * 8;
    const f16* pc = cemb + ((size_t)(b * NU + au)) * HH + g * 8;
    const char* wsrcB = (const char*)Wo_s + lane * 16;

    f32x4 acc[18];
#pragma unroll
    for (int j = 0; j < 18; ++j) acc[j] = (f32x4){0.f, 0.f, 0.f, 0.f};

    const int bB0 = g * 288 + c;  // B-frag: plane g, col j*16+c (longs)

    long a0, a1;  // current chunk A-frags (s=0: k..k+31, s=1: k+32..k+63)

    // ---- prologue: stage B chunk 0, compute A-frags for chunk 0 ----
    {
        for (int ch = w; ch < 18; ch += 8)
            async_copy16(wsrcB + ch * 1024, (char*)&B_s8[0][0] + ch * 1024 + lane * 16);
        f16x8 fv0 = *(const f16x8*)pf;
        f16x8 cv0 = *(const f16x8*)pc;
        f16x8 fv1 = *(const f16x8*)(pf + 32);
        f16x8 cv1 = *(const f16x8*)(pc + 32);
        a0 = tanh_pack8(fv0, cv0);
        a1 = tanh_pack8(fv1, cv1);
        __syncthreads();
    }

    // ---- main loop: one barrier per 64-k chunk ----
    for (int i = 0; i < 8; ++i) {
        const int cur = i & 1, nxt = cur ^ 1;
        f16x8 fv0, cv0, fv1, cv1;
        // B async for i+1 FIRST: flies through the whole MFMA phase
        if (i < 7) {
            const char* wk = wsrcB + (size_t)(i + 1) * 18432;
            for (int ch = w; ch < 18; ch += 8)
                async_copy16(wk + ch * 1024, (char*)&B_s8[nxt][0] + ch * 1024 + lane * 16);
        }
        __builtin_amdgcn_s_setprio(1);
#pragma unroll
        for (int j = 0; j < 18; ++j) {
            long bv = B_s8[cur][bB0 + j * 16];
            acc[j] = __builtin_amdgcn_mfma_f32_16x16x32_fp8_fp8(a0, bv, acc[j], 0, 0, 0);
        }
        __builtin_amdgcn_s_setprio(0);
        // A global loads for i+1 between the two MFMA clusters: latency hides
        // under the s=1 cluster, and the 16 load regs are live only across it.
        if (i < 7) {
            const int kt = (i + 1) * 64;
            fv0 = *(const f16x8*)(pf + kt);
            cv0 = *(const f16x8*)(pc + kt);
            fv1 = *(const f16x8*)(pf + kt + 32);
            cv1 = *(const f16x8*)(pc + kt + 32);
        }
        __builtin_amdgcn_s_setprio(1);
#pragma unroll
        for (int j = 0; j < 18; ++j) {
            long bv = B_s8[cur][bB0 + 1152 + j * 16];
            acc[j] = __builtin_amdgcn_mfma_f32_16x16x32_fp8_fp8(a1, bv, acc[j], 0, 0, 0);
        }
        __builtin_amdgcn_s_setprio(0);
        if (i < 7) {
            a0 = tanh_pack8(fv0, cv0);
            a1 = tanh_pack8(fv1, cv1);
            __syncthreads();
        }
    }

    // undo the Wo x64 pre-scale before LSE
#pragma unroll
    for (int j = 0; j < 18; ++j) acc[j] = acc[j] * INVWOSCL;

    // epilogue: wave owns 16 complete rows -> fully in-wave LSE.
    const int rbase = r0 + w * 16 + g * 4;
#pragma unroll
    for (int r = 0; r < 4; ++r) {
        const int grr = rbase + r;
        const int t = grr / NU, u = grr - t * NU;

        float mx = NEG_INF;
#pragma unroll
        for (int j = 0; j < 17; ++j) {  // j=17 cols 272..287 all >= NV
            int col = j * 16 + c;
            if (col < NV) mx = fmaxf(mx, acc[j][r]);
        }
#pragma unroll
        for (int s = 1; s < 16; s <<= 1) mx = fmaxf(mx, __shfl_xor(mx, s));
        float sum = 0.f;
#pragma unroll
        for (int j = 0; j < 17; ++j) {
            int col = j * 16 + c;
            if (col < NV) sum += __expf(acc[j][r] - mx);
        }
#pragma unroll
        for (int s = 1; s < 16; s <<= 1) sum += __shfl_xor(sum, s);
        float lse = mx + __logf(sum);

        float blankv = __shfl(acc[0][r], lane & 48);  // col 0
        int L = (u < UU) ? labels[b * UU + u] : 0;    // 1..256 (or dummy 0)
        int jl = L >> 4;
        float v = acc[0][r];
#pragma unroll
        for (int j = 1; j < 17; ++j)
            if (jl == j) v = acc[j][r];               // static-index select
        float lexv = __shfl(v, (lane & 48) | (L & 15));

        if (c == 0) {
            float2 ov;
            ov.x = blankv - lse;
            ov.y = (u < UU) ? (lexv - lse) : 0.f;
            *(float2*)&cl_arr[(((size_t)b * TT + t) * NU + u) * 2] = ov;
        }
    }
}

// ---- parallel depth-4 compaction: grid (NG, BB), block 128 (one thread per u).
__global__ __launch_bounds__(128) void k_compact(
    const float* __restrict__ cl, const int* __restrict__ num_frames,
    float* __restrict__ Dg) {
    const int g = blockIdx.x;
    const int b = blockIdx.y;
    const int u = threadIdx.x;
    if (u >= NU) return;
    const int nf = num_frames[b];
    const float2* P = (const float2*)(cl + (size_t)b * TT * NU * 2);

    auto fetch = [&](int t, int uu, float& bb, float& ll) {
        if (uu <= UU) {
            float2 z = P[t * NU + uu];
            bool act = t < nf;
            bb = act ? z.x * LOG2E : 0.f;
            ll = (act && uu < UU) ? z.y * LOG2E : NEG_INF;
        } else {
            bb = NEG_INF;
            ll = NEG_INF;
        }
    };

    const int t0 = g * 4;
    float b0, l0, b1u, l1u, b1u1, l1u1;
    fetch(t0, u, b0, l0);
    fetch(t0 + 1, u, b1u, l1u);
    fetch(t0 + 1, u + 1, b1u1, l1u1);
    float A0 = b0 + b1u;
    float A1 = lae2(l0 + b1u1, b0 + l1u);
    float A2 = l0 + l1u1;
    float B0[3], B1[3], B2[3];
#pragma unroll
    for (int j = 0; j < 3; ++j) {
        float b2v, l2v, b3v, l3v, b3n, l3n;
        fetch(t0 + 2, u + j, b2v, l2v);
        fetch(t0 + 3, u + j, b3v, l3v);
        fetch(t0 + 3, u + j + 1, b3n, l3n);
        B0[j] = b2v + b3v;
        B1[j] = lae2(l2v + b3n, b2v + l3v);
        B2[j] = l2v + l3n;
    }
    float* d = Dg + ((size_t)b * NG + g) * GSTRIDE;
    d[u] = A0 + B0[0];
    d[104 + u] = lae2(A1 + B0[1], A0 + B1[0]);
    d[208 + u] = lse3_2(A2 + B0[2], A1 + B1[1], A0 + B2[0]);
    d[312 + u] = lae2(A2 + B1[2], A1 + B2[1]);
    d[416 + u] = A2 + B2[2];
}

// ---- serial chain: 1 wave per batch, 128 banded-lse5 steps, 8-deep reg ring.
__global__ __launch_bounds__(64) void k_dpser(
    const float* __restrict__ Dg, const int* __restrict__ num_labels,
    float* __restrict__ out) {
    const int b = blockIdx.x;
    const int lane = threadIdx.x;
    const float* D = Dg + (size_t)b * NG * GSTRIDE;
    const int lo_u = lane;
    const int hi_u = 64 + ((lane < 33) ? lane : 0);

    float a_lo = (lane == 0) ? 0.f : NEG_INF;  // alpha[u=lane] (base-2)
    float a_hi = NEG_INF;                      // alpha[u=64+lane], lane<33

    constexpr int R = 8;
    float blo[R][5], bhi[R][5];
#pragma unroll
    for (int g = 0; g < R; ++g)
#pragma unroll
        for (int k = 0; k < 5; ++k) {
            blo[g][k] = D[g * GSTRIDE + k * 104 + lo_u];
            bhi[g][k] = D[g * GSTRIDE + k * 104 + hi_u];
        }

#pragma unroll 8
    for (int g = 0; g < NG; ++g) {
        const int slot = g & (R - 1);
        float el[5], eh[5];
#pragma unroll
        for (int k = 0; k < 5; ++k) {
            el[k] = a_lo + blo[slot][k];
            eh[k] = a_hi + bhi[slot][k];
        }
        const int gp = g + R;
        if (gp < NG) {
#pragma unroll
            for (int k = 0; k < 5; ++k) {
                blo[slot][k] = D[gp * GSTRIDE + k * 104 + lo_u];
                bhi[slot][k] = D[gp * GSTRIDE + k * 104 + hi_u];
            }
        }
        float ml[5], mh[5];
        ml[0] = el[0];
        mh[0] = eh[0];
#pragma unroll
        for (int k = 1; k < 5; ++k) {
            float su = __shfl_up(el[k], k);
            ml[k] = (lane >= k) ? su : NEG_INF;
            float sh = __shfl_up(eh[k], k);
            float xl = __shfl(el[k], 64 - k + lane);  // lo lanes 63..64-k
            mh[k] = (lane >= k) ? sh : xl;
        }
        a_lo = lse5_2(ml[0], ml[1], ml[2], ml[3], ml[4]);
        float nh = lse5_2(mh[0], mh[1], mh[2], mh[3], mh[4]);
        if (lane < 33) a_hi = nh;
    }

    const int nl = num_labels[b];
    float res = (nl < 64) ? __shfl(a_lo, nl) : __shfl(a_hi, nl - 64);
    if (lane == 0) out[b] = -res * LN2;  // back to natural-log domain
}

extern "C" void kernel_launch(void* const* d_in, const int* in_sizes, int n_in,
                              void* d_out, int out_size, void* d_ws, size_t ws_size,
                              hipStream_t stream) {
    const float* frames = (const float*)d_in[0];
    const int* num_frames = (const int*)d_in[1];
    const int* labels = (const int*)d_in[2];
    const int* num_labels = (const int*)d_in[3];
    const float* Wf = (const float*)d_in[4];
    const float* E = (const float*)d_in[5];
    const float* Wo = (const float*)d_in[6];
    float* out = (float*)d_out;

    char* ws = (char*)d_ws;
    size_t off = 0;
    long* Wo_s = (long*)(ws + off); off += (size_t)18432 * 8;                 // 144 KiB
    f16* cemb = (f16*)(ws + off); off += (size_t)BB * NU * HH * 2;            // 388 KiB
    off = (off + 255) & ~(size_t)255;
    f16* fproj = (f16*)(ws + off); off += (size_t)BB * TT * HH * 2;           // 2 MiB
    off = (off + 255) & ~(size_t)255;
    float* cl_arr = (float*)(ws + off); off += (size_t)BB * TT * NU * 2 * 4;  // 1.52 MiB
    off = (off + 255) & ~(size_t)255;
    float* Dg = (float*)(ws + off); off += (size_t)BB * NG * GSTRIDE * 4;     // 1.02 MiB

    hipLaunchKernelGGL(k_front, dim3(425), dim3(256), 0, stream,
                       frames, Wf, Wo, E, labels, fproj, Wo_s, cemb);
    hipLaunchKernelGGL(k_joint, dim3((TT * NU) / 128, BB), dim3(512), 0, stream,
                       fproj, cemb, Wo_s, labels, num_frames, cl_arr);
    hipLaunchKernelGGL(k_compact, dim3(NG, BB), dim3(128), 0, stream,
                       cl_arr, num_frames, Dg);
    hipLaunchKernelGGL(k_dpser, dim3(BB), dim3(64), 0, stream,
                       Dg, num_labels, out);
}

// Round 2
// 187.290 us; speedup vs baseline: 1.0860x; 1.0216x over previous
//
#include <hip/hip_runtime.h>
#include <hip/hip_bf16.h>

// RecognitionLattice: RNN-T style lattice loss.
// k_front: fproj GEMM (direct fp32-Wf transpose staging, f16 out) + Wo->fp8
//          shuffle (NP=272, dead padding tile dropped) + cemb gather (f16)
// -> k_joint: h=tanh(fproj+cemb) packed-f16 -> fp8 @ Wo_fp8, BK=64 K-loop.
//    4-wave blocks (64-row tiles): per-SIMD waves come from DIFFERENT blocks
//    (independent barrier groups) -> tanh/MFMA phases of distinct blocks
//    overlap on each SIMD. A-frags computed in registers (lane's tanh output
//    == its MFMA A-frag), B-only double-buffered LDS via global_load_lds.
//    acc[17] (dead j=17 tile removed), launch_bounds(256,4) for 4 blocks/CU.
// -> k_compact: parallel depth-4 semiring compaction -> Dg
// -> k_dpser: 1 wave/batch serial chain, 128 banded-lse5 steps, 8-deep reg ring.

#define BB 4
#define TT 512
#define UU 96
#define FF 512
#define HH 512
#define VV 256
#define NV (VV + 1)    // 257 vocab incl. blank
#define NU (UU + 1)    // 97 lattice rows per t
#define NP 272         // 17*16 padded N (257 -> 272)
#define NEG_INF (-1e30f)
#define LOG2E 1.4426950408889634f
#define LN2 0.6931471805599453f
#define NG 128         // groups of 4 t-steps
#define GSTRIDE 520    // 5*104 floats per group operator
#define WOSCL 64.0f    // Wo pre-scale into fp8 normal range
#define INVWOSCL 0.015625f
#define BCHUNK 17408   // bytes per 64-k B chunk = 64*272 fp8
#define BLONGS 2176    // longs per chunk

typedef _Float16 f16;
typedef __attribute__((ext_vector_type(8))) _Float16 f16x8;
typedef __bf16 bf16;
typedef __bf16 bf16x8 __attribute__((ext_vector_type(8)));
typedef float f32x4 __attribute__((ext_vector_type(4)));

__device__ __forceinline__ f16x8 splat8(float s) {
    f16 v = (f16)s;
    f16x8 r = {v, v, v, v, v, v, v, v};
    return r;
}

// tanh via clamped odd polynomial in PACKED f16 (v_pk_* dual-issue), then
// fp8 e4m3 pack. Max poly err ~0.007 on [-2,2]; f16 intermediate err ~1e-3
// << fp8 output quantization.
__device__ __forceinline__ long tanh_pack8(f16x8 fv8, f16x8 cv8) {
    f16x8 x = fv8 + cv8;
    x = __builtin_elementwise_min(__builtin_elementwise_max(x, splat8(-2.0f)),
                                  splat8(2.0f));
    f16x8 y = x * x;
    f16x8 q = y * splat8(-0.0067528f) + splat8(0.0700672f);
    q = y * q + splat8(-0.301720f);
    q = y * q + splat8(1.0f);
    f16x8 t = x * q;
    int lo = 0, hi = 0;
    lo = __builtin_amdgcn_cvt_pk_fp8_f32((float)t[0], (float)t[1], lo, false);
    lo = __builtin_amdgcn_cvt_pk_fp8_f32((float)t[2], (float)t[3], lo, true);
    hi = __builtin_amdgcn_cvt_pk_fp8_f32((float)t[4], (float)t[5], hi, false);
    hi = __builtin_amdgcn_cvt_pk_fp8_f32((float)t[6], (float)t[7], hi, true);
    return (long)(((unsigned long long)(unsigned int)lo) |
                  (((unsigned long long)(unsigned int)hi) << 32));
}

// pack 8 floats -> 8 fp8 e4m3 (for Wo prep)
__device__ __forceinline__ long pack_fp8x8(const float* v) {
    int lo = 0, hi = 0;
    lo = __builtin_amdgcn_cvt_pk_fp8_f32(v[0], v[1], lo, false);
    lo = __builtin_amdgcn_cvt_pk_fp8_f32(v[2], v[3], lo, true);
    hi = __builtin_amdgcn_cvt_pk_fp8_f32(v[4], v[5], hi, false);
    hi = __builtin_amdgcn_cvt_pk_fp8_f32(v[6], v[7], hi, true);
    return (long)(((unsigned long long)(unsigned int)lo) |
                  (((unsigned long long)(unsigned int)hi) << 32));
}

// base-2 log-domain ops (inputs/outputs already scaled by log2(e))
__device__ __forceinline__ float lae2(float x, float y) {
    float m = fmaxf(x, y);
    float d = fminf(x, y) - m;
    return m + __builtin_amdgcn_logf(1.0f + __builtin_amdgcn_exp2f(d));
}

__device__ __forceinline__ float lse3_2(float x, float y, float z) {
    float m = fmaxf(fmaxf(x, y), z);
    float s = __builtin_amdgcn_exp2f(x - m) + __builtin_amdgcn_exp2f(y - m) +
              __builtin_amdgcn_exp2f(z - m);
    return m + __builtin_amdgcn_logf(s);
}

__device__ __forceinline__ float lse5_2(float a, float b, float c, float d, float e) {
    float m = fmaxf(fmaxf(fmaxf(a, b), fmaxf(c, d)), e);
    float s = __builtin_amdgcn_exp2f(a - m) + __builtin_amdgcn_exp2f(b - m) +
              __builtin_amdgcn_exp2f(c - m) + __builtin_amdgcn_exp2f(d - m) +
              __builtin_amdgcn_exp2f(e - m);
    return m + __builtin_amdgcn_logf(s);
}

__device__ __forceinline__ void async_copy16(const void* g, void* l) {
    __builtin_amdgcn_global_load_lds(
        (const __attribute__((address_space(1))) unsigned int*)g,
        (__attribute__((address_space(3))) unsigned int*)l, 16, 0, 0);
}

// ---- front: fproj GEMM + Wo->fp8 shuffle + cemb gather
__global__ __launch_bounds__(256, 2) void k_front(
    const float* __restrict__ frames, const float* __restrict__ Wf,
    const float* __restrict__ Wo, const float* __restrict__ E,
    const int* __restrict__ labels, f16* __restrict__ fproj,
    long* __restrict__ Wo_s, f16* __restrict__ cemb) {
    __shared__ bf16 Alds[64 * 40];
    __shared__ bf16 Blds[64 * 40];
    const int blk = blockIdx.x;
    const int tid = threadIdx.x;

    if (blk < 256) {
        const int r0 = (blk & 31) * 64;
        const int n0 = (blk >> 5) * 64;
        const int lane = tid & 63, w = tid >> 6;
        const int c = lane & 15, g = lane >> 4;

        const int srow = tid >> 2, sko = (tid & 3) * 8;
        const float* fptr = frames + (size_t)(r0 + srow) * FF + sko;
        const int q = tid >> 6, c64 = tid & 63;  // B-transpose staging coords

        f32x4 acc[4];
#pragma unroll
        for (int j = 0; j < 4; ++j) acc[j] = (f32x4){0.f, 0.f, 0.f, 0.f};

        for (int kt = 0; kt < FF; kt += 32) {
            float4 f1 = *(const float4*)(fptr + kt);
            float4 f2 = *(const float4*)(fptr + kt + 4);
            bf16x8 av = {(bf16)f1.x, (bf16)f1.y, (bf16)f1.z, (bf16)f1.w,
                         (bf16)f2.x, (bf16)f2.y, (bf16)f2.z, (bf16)f2.w};
            *(bf16x8*)&Alds[srow * 40 + sko] = av;
#pragma unroll
            for (int p = 0; p < 8; ++p) {
                float v = Wf[(size_t)(kt + q * 8 + p) * HH + n0 + c64];
                Blds[c64 * 40 + q * 8 + p] = (bf16)v;
            }
            __syncthreads();
            const int m = w * 16;
            bf16x8 af = *(const bf16x8*)&Alds[(m + c) * 40 + g * 8];
#pragma unroll
            for (int j = 0; j < 4; ++j) {
                bf16x8 bv = *(const bf16x8*)&Blds[(j * 16 + c) * 40 + g * 8];
                acc[j] = __builtin_amdgcn_mfma_f32_16x16x32_bf16(af, bv, acc[j], 0, 0, 0);
            }
            __syncthreads();
        }
        const int m = w * 16;
#pragma unroll
        for (int j = 0; j < 4; ++j)
#pragma unroll
            for (int r = 0; r < 4; ++r)
                fproj[(size_t)(r0 + m + g * 4 + r) * HH + n0 + j * 16 + c] = (f16)acc[j][r];
    } else if (blk < 324) {
        int idx = (blk - 256) * 256 + tid;  // 0..17407
        int n = idx % NP;
        int rest = idx / NP;
        int kg = rest & 3;
        int k32 = rest >> 2;
        float v[8];
#pragma unroll
        for (int e = 0; e < 8; ++e) {
            int k = k32 * 32 + kg * 8 + e;
            v[e] = (n < NV) ? Wo[k * NV + n] * WOSCL : 0.f;
        }
        Wo_s[idx] = pack_fp8x8(v);
    } else {
        int u = blk - 324;  // 0..96
        for (int b = 0; b < BB; ++b) {
            int ctx = (u == 0) ? 0 : labels[b * UU + (u - 1)];
            const float* src = E + (size_t)ctx * HH;
            f16* dst = cemb + ((size_t)b * NU + u) * HH;
            for (int i = tid; i < HH; i += 256) dst[i] = (f16)src[i];
        }
    }
}

// ---- joint: logits = tanh(fproj[t]+cemb[u]) @ Wo  [fp8 MFMA, BK=64 K-loop]
// grid (776, B), block 256 = 4 waves = 4 M-slots of 16 rows; each wave owns
// 16 rows x 272 cols (acc[17] f32x4 = 68 regs). A-fragments in registers:
// lane (c=lane&15, g=lane>>4) tanh-packs row (w*16+c), k-octet g directly
// into the MFMA A operand. B double-buffered via global_load_lds. One barrier
// per 64-k chunk. Small blocks -> multiple independent barrier groups per
// SIMD -> tanh(VALU) of one block overlaps MFMA of another.
__global__ __launch_bounds__(256, 4) void k_joint(
    const f16* __restrict__ fproj, const f16* __restrict__ cemb,
    const long* __restrict__ Wo_s, const int* __restrict__ labels,
    const int* __restrict__ num_frames, float* __restrict__ cl_arr) {
    __shared__ long B_s8[2][BLONGS];  // 2 x 17408 B; [s(k32)][kg][n] longs

    const int tid = threadIdx.x;
    const int b = blockIdx.y;
    const int r0 = blockIdx.x * 64;
    const int nf = num_frames[b];
    if (r0 / NU >= nf) return;  // whole tile beyond active frames: outputs unused

    const int lane = tid & 63, w = tid >> 6;
    const int c = lane & 15, g = lane >> 4;

    // This lane's A row and k-octet: row = w*16 + c, k = g*8 + s*32 + i*64.
    const int gr = r0 + w * 16 + c;
    const int at = gr / NU, au = gr - at * NU;
    const f16* pf = fproj + ((size_t)(b * TT + at)) * HH + g * 8;
    const f16* pc = cemb + ((size_t)(b * NU + au)) * HH + g * 8;
    const char* wsrcB = (const char*)Wo_s + lane * 16;

    f32x4 acc[17];
#pragma unroll
    for (int j = 0; j < 17; ++j) acc[j] = (f32x4){0.f, 0.f, 0.f, 0.f};

    const int bB0 = g * NP + c;  // B-frag: plane g, col j*16+c (longs)

    long a0, a1;  // current chunk A-frags (s=0: k..k+31, s=1: k+32..k+63)

    // ---- prologue: stage B chunk 0, compute A-frags for chunk 0 ----
    {
        for (int ch = w; ch < 17; ch += 4)
            async_copy16(wsrcB + ch * 1024, (char*)&B_s8[0][0] + ch * 1024 + lane * 16);
        f16x8 fv0 = *(const f16x8*)pf;
        f16x8 cv0 = *(const f16x8*)pc;
        f16x8 fv1 = *(const f16x8*)(pf + 32);
        f16x8 cv1 = *(const f16x8*)(pc + 32);
        a0 = tanh_pack8(fv0, cv0);
        a1 = tanh_pack8(fv1, cv1);
        __syncthreads();
    }

    // ---- main loop: one barrier per 64-k chunk ----
    for (int i = 0; i < 8; ++i) {
        const int cur = i & 1, nxt = cur ^ 1;
        f16x8 fv0, cv0, fv1, cv1;
        // B async + A loads for i+1 FIRST: fly through the s=0 MFMA cluster
        if (i < 7) {
            const char* wk = wsrcB + (size_t)(i + 1) * BCHUNK;
            for (int ch = w; ch < 17; ch += 4)
                async_copy16(wk + ch * 1024, (char*)&B_s8[nxt][0] + ch * 1024 + lane * 16);
            const int kt = (i + 1) * 64;
            fv0 = *(const f16x8*)(pf + kt);
            cv0 = *(const f16x8*)(pc + kt);
            fv1 = *(const f16x8*)(pf + kt + 32);
            cv1 = *(const f16x8*)(pc + kt + 32);
        }
        __builtin_amdgcn_s_setprio(1);
#pragma unroll
        for (int j = 0; j < 17; ++j) {
            long bv = B_s8[cur][bB0 + j * 16];
            acc[j] = __builtin_amdgcn_mfma_f32_16x16x32_fp8_fp8(a0, bv, acc[j], 0, 0, 0);
        }
        __builtin_amdgcn_s_setprio(0);
        // tanh between the clusters: loads had the whole s=0 cluster to land;
        // only 4 regs (a0n,a1n) stay live across the s=1 cluster.
        long a0n, a1n;
        if (i < 7) {
            a0n = tanh_pack8(fv0, cv0);
            a1n = tanh_pack8(fv1, cv1);
        }
        __builtin_amdgcn_s_setprio(1);
#pragma unroll
        for (int j = 0; j < 17; ++j) {
            long bv = B_s8[cur][bB0 + 1088 + j * 16];
            acc[j] = __builtin_amdgcn_mfma_f32_16x16x32_fp8_fp8(a1, bv, acc[j], 0, 0, 0);
        }
        __builtin_amdgcn_s_setprio(0);
        if (i < 7) {
            a0 = a0n;
            a1 = a1n;
            __syncthreads();
        }
    }

    // undo the Wo x64 pre-scale before LSE
#pragma unroll
    for (int j = 0; j < 17; ++j) acc[j] = acc[j] * INVWOSCL;

    // epilogue: wave owns 16 complete rows -> fully in-wave LSE.
    const int rbase = r0 + w * 16 + g * 4;
#pragma unroll
    for (int r = 0; r < 4; ++r) {
        const int grr = rbase + r;
        const int t = grr / NU, u = grr - t * NU;

        float mx = NEG_INF;
#pragma unroll
        for (int j = 0; j < 17; ++j) {
            int col = j * 16 + c;
            if (col < NV) mx = fmaxf(mx, acc[j][r]);
        }
#pragma unroll
        for (int s = 1; s < 16; s <<= 1) mx = fmaxf(mx, __shfl_xor(mx, s));
        float sum = 0.f;
#pragma unroll
        for (int j = 0; j < 17; ++j) {
            int col = j * 16 + c;
            if (col < NV) sum += __expf(acc[j][r] - mx);
        }
#pragma unroll
        for (int s = 1; s < 16; s <<= 1) sum += __shfl_xor(sum, s);
        float lse = mx + __logf(sum);

        float blankv = __shfl(acc[0][r], lane & 48);  // col 0
        int L = (u < UU) ? labels[b * UU + u] : 0;    // 1..256 (or dummy 0)
        int jl = L >> 4;
        float v = acc[0][r];
#pragma unroll
        for (int j = 1; j < 17; ++j)
            if (jl == j) v = acc[j][r];               // static-index select
        float lexv = __shfl(v, (lane & 48) | (L & 15));

        if (c == 0) {
            float2 ov;
            ov.x = blankv - lse;
            ov.y = (u < UU) ? (lexv - lse) : 0.f;
            *(float2*)&cl_arr[(((size_t)b * TT + t) * NU + u) * 2] = ov;
        }
    }
}

// ---- parallel depth-4 compaction: grid (NG, BB), block 128 (one thread per u).
__global__ __launch_bounds__(128) void k_compact(
    const float* __restrict__ cl, const int* __restrict__ num_frames,
    float* __restrict__ Dg) {
    const int g = blockIdx.x;
    const int b = blockIdx.y;
    const int u = threadIdx.x;
    if (u >= NU) return;
    const int nf = num_frames[b];
    const float2* P = (const float2*)(cl + (size_t)b * TT * NU * 2);

    auto fetch = [&](int t, int uu, float& bb, float& ll) {
        if (uu <= UU) {
            float2 z = P[t * NU + uu];
            bool act = t < nf;
            bb = act ? z.x * LOG2E : 0.f;
            ll = (act && uu < UU) ? z.y * LOG2E : NEG_INF;
        } else {
            bb = NEG_INF;
            ll = NEG_INF;
        }
    };

    const int t0 = g * 4;
    float b0, l0, b1u, l1u, b1u1, l1u1;
    fetch(t0, u, b0, l0);
    fetch(t0 + 1, u, b1u, l1u);
    fetch(t0 + 1, u + 1, b1u1, l1u1);
    float A0 = b0 + b1u;
    float A1 = lae2(l0 + b1u1, b0 + l1u);
    float A2 = l0 + l1u1;
    float B0[3], B1[3], B2[3];
#pragma unroll
    for (int j = 0; j < 3; ++j) {
        float b2v, l2v, b3v, l3v, b3n, l3n;
        fetch(t0 + 2, u + j, b2v, l2v);
        fetch(t0 + 3, u + j, b3v, l3v);
        fetch(t0 + 3, u + j + 1, b3n, l3n);
        B0[j] = b2v + b3v;
        B1[j] = lae2(l2v + b3n, b2v + l3v);
        B2[j] = l2v + l3n;
    }
    float* d = Dg + ((size_t)b * NG + g) * GSTRIDE;
    d[u] = A0 + B0[0];
    d[104 + u] = lae2(A1 + B0[1], A0 + B1[0]);
    d[208 + u] = lse3_2(A2 + B0[2], A1 + B1[1], A0 + B2[0]);
    d[312 + u] = lae2(A2 + B1[2], A1 + B2[1]);
    d[416 + u] = A2 + B2[2];
}

// ---- serial chain: 1 wave per batch, 128 banded-lse5 steps, 8-deep reg ring.
__global__ __launch_bounds__(64) void k_dpser(
    const float* __restrict__ Dg, const int* __restrict__ num_labels,
    float* __restrict__ out) {
    const int b = blockIdx.x;
    const int lane = threadIdx.x;
    const float* D = Dg + (size_t)b * NG * GSTRIDE;
    const int lo_u = lane;
    const int hi_u = 64 + ((lane < 33) ? lane : 0);

    float a_lo = (lane == 0) ? 0.f : NEG_INF;  // alpha[u=lane] (base-2)
    float a_hi = NEG_INF;                      // alpha[u=64+lane], lane<33

    constexpr int R = 8;
    float blo[R][5], bhi[R][5];
#pragma unroll
    for (int g = 0; g < R; ++g)
#pragma unroll
        for (int k = 0; k < 5; ++k) {
            blo[g][k] = D[g * GSTRIDE + k * 104 + lo_u];
            bhi[g][k] = D[g * GSTRIDE + k * 104 + hi_u];
        }

#pragma unroll 8
    for (int g = 0; g < NG; ++g) {
        const int slot = g & (R - 1);
        float el[5], eh[5];
#pragma unroll
        for (int k = 0; k < 5; ++k) {
            el[k] = a_lo + blo[slot][k];
            eh[k] = a_hi + bhi[slot][k];
        }
        const int gp = g + R;
        if (gp < NG) {
#pragma unroll
            for (int k = 0; k < 5; ++k) {
                blo[slot][k] = D[gp * GSTRIDE + k * 104 + lo_u];
                bhi[slot][k] = D[gp * GSTRIDE + k * 104 + hi_u];
            }
        }
        float ml[5], mh[5];
        ml[0] = el[0];
        mh[0] = eh[0];
#pragma unroll
        for (int k = 1; k < 5; ++k) {
            float su = __shfl_up(el[k], k);
            ml[k] = (lane >= k) ? su : NEG_INF;
            float sh = __shfl_up(eh[k], k);
            float xl = __shfl(el[k], 64 - k + lane);  // lo lanes 63..64-k
            mh[k] = (lane >= k) ? sh : xl;
        }
        a_lo = lse5_2(ml[0], ml[1], ml[2], ml[3], ml[4]);
        float nh = lse5_2(mh[0], mh[1], mh[2], mh[3], mh[4]);
        if (lane < 33) a_hi = nh;
    }

    const int nl = num_labels[b];
    float res = (nl < 64) ? __shfl(a_lo, nl) : __shfl(a_hi, nl - 64);
    if (lane == 0) out[b] = -res * LN2;  // back to natural-log domain
}

extern "C" void kernel_launch(void* const* d_in, const int* in_sizes, int n_in,
                              void* d_out, int out_size, void* d_ws, size_t ws_size,
                              hipStream_t stream) {
    const float* frames = (const float*)d_in[0];
    const int* num_frames = (const int*)d_in[1];
    const int* labels = (const int*)d_in[2];
    const int* num_labels = (const int*)d_in[3];
    const float* Wf = (const float*)d_in[4];
    const float* E = (const float*)d_in[5];
    const float* Wo = (const float*)d_in[6];
    float* out = (float*)d_out;

    char* ws = (char*)d_ws;
    size_t off = 0;
    long* Wo_s = (long*)(ws + off); off += (size_t)17408 * 8;                 // 136 KiB
    f16* cemb = (f16*)(ws + off); off += (size_t)BB * NU * HH * 2;            // 388 KiB
    off = (off + 255) & ~(size_t)255;
    f16* fproj = (f16*)(ws + off); off += (size_t)BB * TT * HH * 2;           // 2 MiB
    off = (off + 255) & ~(size_t)255;
    float* cl_arr = (float*)(ws + off); off += (size_t)BB * TT * NU * 2 * 4;  // 1.52 MiB
    off = (off + 255) & ~(size_t)255;
    float* Dg = (float*)(ws + off); off += (size_t)BB * NG * GSTRIDE * 4;     // 1.02 MiB

    hipLaunchKernelGGL(k_front, dim3(421), dim3(256), 0, stream,
                       frames, Wf, Wo, E, labels, fproj, Wo_s, cemb);
    hipLaunchKernelGGL(k_joint, dim3((TT * NU) / 64, BB), dim3(256), 0, stream,
                       fproj, cemb, Wo_s, labels, num_frames, cl_arr);
    hipLaunchKernelGGL(k_compact, dim3(NG, BB), dim3(128), 0, stream,
                       cl_arr, num_frames, Dg);
    hipLaunchKernelGGL(k_dpser, dim3(BB), dim3(64), 0, stream,
                       Dg, num_labels, out);
}